// Round 1
// baseline (125.005 us; speedup 1.0000x reference)
//
#include <hip/hip_runtime.h>

// ConvTranspose3d (2,64,32^3) fp32 -> (2,32,66^3), stride2 pad1 outpad1 dil2 k3.
// Odd-grid MFMA: out[n,co,2dp+1,2hp+1,2wp+1] = bias[co] +
//   sum_{ci,kd,kh,kw} x[n,ci,dp+1-kd,hp+1-kh,wp+1-kw] * w[ci,co,kd,kh,kw]
// R14: single fused hot kernel.
//  - x16 HBM round-trip eliminated: each block repacks its 12 x-rows
//    fp32->f16 straight into LDS (same layout the DMA staged in R13).
//  - all pure-bias output rows folded into convt epilogue (waves 2/3 +
//    dp31 extras); prep is now just the 216-block w-pack.
//  - nontemporal output stores keep x/wA resident in L2.
// MFMA core / split-K / C-D mapping identical to the verified R13 kernel.

#define DOUT 66
#define PL (DOUT*DOUT)                  // 4356 floats/plane
#define ROW_B 4352                      // bytes per (id,ih) LDS row: 8ccg*34iwl*8ci*2

typedef _Float16 half8   __attribute__((ext_vector_type(8)));
typedef float    floatx16 __attribute__((ext_vector_type(16)));
typedef float    floatx4  __attribute__((ext_vector_type(4)));
typedef float    floatx2  __attribute__((ext_vector_type(2)));

// ---- k1: w-pack only. wA[cc 4][tap 27][lane 64][8 f16]; lane=co+32*khalf ----
__global__ void __launch_bounds__(256) wprep(const float* __restrict__ w,
                                             _Float16* __restrict__ wA)
{
    int o = blockIdx.x * 256 + threadIdx.x;   // < 55296 = 216*256 exactly
    int j = o & 7;
    int tmp = o >> 3;
    int lane = tmp & 63;
    int g = tmp >> 6;                         // cc*27 + tap
    int cc = g / 27, tap = g - cc * 27;
    int co = lane & 31, khalf = lane >> 5;
    int ci = cc * 16 + khalf * 8 + j;
    wA[o] = (_Float16)w[ci * 864 + co * 27 + tap];
}

// ---- k2: fused repack + conv + full output (values + all bias rows) ----
__global__ void __launch_bounds__(256, 3) convt(
    const float* __restrict__ x, const _Float16* __restrict__ wA,
    const float* __restrict__ bias, float* __restrict__ out)
{
    __shared__ __align__(16) unsigned char xlds[52224];   // 12 rows x 4352 B

    const int tid  = threadIdx.x;
    const int lane = tid & 63;
    const int wv   = tid >> 6;           // wave = K chunk (16 ci)

    unsigned b = blockIdx.x;             // 1024: xcd(3) | dp(5) | hq2(2)
    const unsigned xcd = b & 7u;
    const int n   = (int)(xcd & 1u);
    const unsigned rest = b >> 3;
    const int dp  = (int)(rest & 31u);
    const int hq2 = (int)(rest >> 5);
    const int hpg = (int)((xcd >> 1) * 4 + hq2);   // 0..15
    const int hpb = hpg * 2;             // hp0 = hpb, hp1 = hpb+1

    // ---- repack: x fp32 -> LDS f16 rows [r 12][ccg 8][iwl 34][ci8 8] ----
    // 768 quad-tasks (3/thread): task (r, ccg, gq) = 8x dwordx4 (8 ci x 4 iw)
    // -> 16 cvt_pkrtz -> 4 ds_write_b128 at iwl = 4*gq+1 .. +4.
    // r = k*4+wv is wave-uniform -> invalid-row branch non-divergent.
    const float* xn = x + (size_t)n * 2097152;
    const int gq  = tid & 7;             // iw quad index 0..7 (iw = 4*gq..4*gq+3)
    const int ccg = (tid >> 3) & 7;      // ci group (8 ci)
    #pragma unroll
    for (int k = 0; k < 3; ++k) {
        const int r  = k * 4 + wv;
        const int id = dp  - 1 + (r >> 2);
        const int ih = hpb - 1 + (r & 3);
        unsigned char* dst = xlds + r * ROW_B + ccg * 544 + (gq * 4 + 1) * 16;
        if (((unsigned)id < 32u) & ((unsigned)ih < 32u)) {
            const float* src = xn + ccg * 262144 + (id * 32 + ih) * 32 + gq * 4;
            floatx4 f0 = *(const floatx4*)(src);
            floatx4 f1 = *(const floatx4*)(src + 32768);
            floatx4 f2 = *(const floatx4*)(src + 2 * 32768);
            floatx4 f3 = *(const floatx4*)(src + 3 * 32768);
            floatx4 f4 = *(const floatx4*)(src + 4 * 32768);
            floatx4 f5 = *(const floatx4*)(src + 5 * 32768);
            floatx4 f6 = *(const floatx4*)(src + 6 * 32768);
            floatx4 f7 = *(const floatx4*)(src + 7 * 32768);
            #pragma unroll
            for (int m = 0; m < 4; ++m) {
                unsigned p0 = __builtin_bit_cast(unsigned,
                    __builtin_amdgcn_cvt_pkrtz(f0[m], f1[m]));
                unsigned p1 = __builtin_bit_cast(unsigned,
                    __builtin_amdgcn_cvt_pkrtz(f2[m], f3[m]));
                unsigned p2 = __builtin_bit_cast(unsigned,
                    __builtin_amdgcn_cvt_pkrtz(f4[m], f5[m]));
                unsigned p3 = __builtin_bit_cast(unsigned,
                    __builtin_amdgcn_cvt_pkrtz(f6[m], f7[m]));
                *(uint4*)(dst + m * 16) = make_uint4(p0, p1, p2, p3);
            }
        } else {
            #pragma unroll
            for (int m = 0; m < 4; ++m)
                *(uint4*)(dst + m * 16) = make_uint4(0, 0, 0, 0);
        }
    }
    // halo zeros: 12 rows x 8 ccg x {iwl 0, 33}
    if (tid < 192) {
        const int r   = tid >> 4;
        const int rem = tid & 15;
        const int cg  = rem >> 1, side = rem & 1;
        *(uint4*)(xlds + r * ROW_B + cg * 544 + (side ? 33 * 16 : 0)) =
            make_uint4(0, 0, 0, 0);
    }

    // ---- A: 27 uint4 batch load (L2-hot wA) ----
    uint4 A[27];
    const _Float16* wl = wA + ((size_t)wv * 27 * 64 + lane) * 8;
    #pragma unroll
    for (int t = 0; t < 27; ++t) A[t] = *(const uint4*)(wl + t * 512);

    __syncthreads();

    // ---- K-loop: 54 MFMAs (27 taps x 2 hp tiles), pure ds_read_b128 ----
    const int wp    = lane & 31;
    const int khalf = lane >> 5;
    const int cbase = (2 * wv + khalf) * 544 + wp * 16;

    floatx16 acc0 = {}, acc1 = {};
    #pragma unroll
    for (int kd = 0; kd < 3; ++kd)
    #pragma unroll
    for (int kh = 0; kh < 3; ++kh)
    #pragma unroll
    for (int kw = 0; kw < 3; ++kw) {
        const int tap  = (kd * 3 + kh) * 3 + kw;
        const int row0 = (2 - kd) * 4 + (2 - kh);   // tile0; tile1 = row0+1
        const uint4* bp0 = (const uint4*)(xlds + row0 * ROW_B + cbase + (2 - kw) * 16);
        acc0 = __builtin_amdgcn_mfma_f32_32x32x16_f16(
            __builtin_bit_cast(half8, A[tap]),
            __builtin_bit_cast(half8, bp0[0]), acc0, 0, 0, 0);
        const uint4* bp1 = (const uint4*)((const char*)bp0 + ROW_B);
        acc1 = __builtin_amdgcn_mfma_f32_32x32x16_f16(
            __builtin_bit_cast(half8, A[tap]),
            __builtin_bit_cast(half8, bp1[0]), acc1, 0, 0, 0);
    }

    // ---- distributed split-K reduce: wave0 finalizes tile0, wave1 tile1 ----
    __syncthreads();
    float* part = (float*)xlds;          // part[(w*2+t)*16 + r][lane], 32 KB
    if (wv != 0) {
        #pragma unroll
        for (int r = 0; r < 16; ++r)
            part[((wv * 2 + 0) * 16 + r) * 64 + lane] = acc0[r];
    }
    if (wv != 1) {
        #pragma unroll
        for (int r = 0; r < 16; ++r)
            part[((wv * 2 + 1) * 16 + r) * 64 + lane] = acc1[r];
    }
    __syncthreads();

    const int od = 2 * dp + 1;
    if (wv <= 1) {
        float s[16];
        #pragma unroll
        for (int r = 0; r < 16; ++r) {
            s[r] = (wv == 0) ? acc0[r] : acc1[r];
            #pragma unroll
            for (int w2 = 0; w2 < 4; ++w2) {
                if (w2 == wv) continue;
                s[r] += part[((w2 * 2 + wv) * 16 + r) * 64 + lane];
            }
        }
        const int oh = 2 * (hpb + wv) + 1;           // value (conv) row
        #pragma unroll
        for (int r = 0; r < 16; ++r) {
            const int co = (r & 3) + 8 * (r >> 2) + 4 * khalf;   // verified C/D map
            const float bv = bias[co];
            floatx2* orow = (floatx2*)(out +
                ((size_t)(n * 32 + co) * DOUT + od) * PL + oh * DOUT);
            floatx2 vv = {bv, s[r] + bv};
            __builtin_nontemporal_store(vv, orow + wp);
            if (wp == 31) {
                floatx2 bb2 = {bv, bv};
                __builtin_nontemporal_store(bb2, orow + 32);
            }
        }
    } else {
        // pure-bias rows. Coverage per (n,dp,hpg):
        //  odd plane od:    even rows wv2: 4hpg, wv3: 4hpg+2; tails hpg15: 64/65
        //  even plane od-1: wv2: {4hpg,4hpg+1}, wv3: {4hpg+2,4hpg+3}; tails 64/65
        //  dp31 extras:     planes 64,65 same row split; tails hpg15: 64/65
        const bool tails = (hpg == 15);
        const bool extra = (dp == 31);
        const int ohA = (wv == 2) ? 2 * hpb : 2 * hpb + 2;
        const int ohT = (wv == 2) ? 64 : 65;
        const int e0  = 4 * hpg + ((wv == 2) ? 0 : 2);
        auto putrow = [&](float* plane, int oh, floatx2 bb) {
            floatx2* rw = (floatx2*)(plane + oh * DOUT);
            __builtin_nontemporal_store(bb, rw + wp);
            if (wp == 31) __builtin_nontemporal_store(bb, rw + 32);
        };
        #pragma unroll
        for (int r = 0; r < 16; ++r) {
            const int co = (r & 3) + 8 * (r >> 2) + 4 * khalf;
            const float bv = bias[co];
            const floatx2 bb = {bv, bv};
            float* pc    = out + (size_t)(n * 32 + co) * ((size_t)DOUT * PL);
            float* podd  = pc + (size_t)od * PL;
            float* peven = pc + (size_t)(od - 1) * PL;
            putrow(podd, ohA, bb);
            if (tails) putrow(podd, ohT, bb);
            putrow(peven, e0, bb);
            putrow(peven, e0 + 1, bb);
            if (tails) putrow(peven, ohT, bb);
            if (extra) {
                float* p64 = pc + (size_t)64 * PL;
                float* p65 = pc + (size_t)65 * PL;
                putrow(p64, e0, bb);
                putrow(p64, e0 + 1, bb);
                putrow(p65, e0, bb);
                putrow(p65, e0 + 1, bb);
                if (tails) {
                    putrow(p64, ohT, bb);
                    putrow(p65, ohT, bb);
                }
            }
        }
    }
}

extern "C" void kernel_launch(void* const* d_in, const int* in_sizes, int n_in,
                              void* d_out, int out_size, void* d_ws, size_t ws_size,
                              hipStream_t stream) {
    const float* x    = (const float*)d_in[0];
    const float* wgt  = (const float*)d_in[1];
    const float* bias = (const float*)d_in[2];
    float* out = (float*)d_out;
    _Float16* wA = (_Float16*)d_ws;      // 110592 B

    wprep<<<216, 256, 0, stream>>>(wgt, wA);
    convt<<<1024, 256, 0, stream>>>(x, wA, bias, out);
}